// Round 2
// baseline (1561.020 us; speedup 1.0000x reference)
//
#include <hip/hip_runtime.h>
#include <hip/hip_fp16.h>

typedef _Float16 half8 __attribute__((ext_vector_type(8)));
typedef float floatx4 __attribute__((ext_vector_type(4)));

#define GLD(gp, lp) __builtin_amdgcn_global_load_lds( \
    (const __attribute__((address_space(1))) void*)(gp), \
    (__attribute__((address_space(3))) void*)(lp), 16, 0, 0)

static constexpr int B_ = 8, D_ = 512, T_ = 2048, K_ = 8192;
static constexpr size_t ZSZ = (size_t)B_ * D_ * T_;   // 8388608 elems; one output segment
static constexpr size_t SEGB = ZSZ * 4;               // 33,554,432 bytes per segment
static constexpr float MARGIN = 0.02f;                // f16 screen err ~4e-3; 2x + slack

// ---------------- prep: transpose z (B,D,T) -> encT (BT,D) in f32 + f16 ----------------
__global__ __launch_bounds__(256) void k_prep_z(const float* __restrict__ z,
                                                float* __restrict__ encT,
                                                _Float16* __restrict__ encTh) {
  int bid = blockIdx.x;
  int db = bid & 7, tb = (bid >> 3) & 31, b = bid >> 8;   // 8 x 32 x 8 = 2048 blocks
  int d0 = db * 64, t0 = tb * 64;
  __shared__ float tz[64][65];
  int tid = threadIdx.x, w = tid >> 6, lane = tid & 63;
#pragma unroll
  for (int it = 0; it < 16; ++it) {
    int dl = it * 4 + w;
    tz[dl][lane] = z[((size_t)(b * D_ + d0 + dl)) * T_ + t0 + lane];  // coalesced along t
  }
  __syncthreads();
#pragma unroll
  for (int it = 0; it < 16; ++it) {
    int tl = it * 4 + w;
    size_t bt = (size_t)b * T_ + t0 + tl;
    float v = tz[lane][tl];                                // bank-spread (stride 65)
    encT[bt * D_ + d0 + lane] = v;                         // coalesced along d
    encTh[bt * D_ + d0 + lane] = (_Float16)v;
  }
}

// ---------------- prep: codebook norms (f64) + normalized f16 codebook ----------------
__global__ __launch_bounds__(256) void k_prep_cb(const float* __restrict__ cb,
                                                 _Float16* __restrict__ cbh,
                                                 double* __restrict__ nrm) {
  int k = blockIdx.x;
  int tid = threadIdx.x;
  float c0 = cb[(size_t)k * 512 + tid];
  float c1 = cb[(size_t)k * 512 + 256 + tid];
  double s = (double)c0 * c0 + (double)c1 * c1;
#pragma unroll
  for (int m = 1; m < 64; m <<= 1) s += __shfl_xor(s, m, 64);
  __shared__ double part[4];
  if ((tid & 63) == 0) part[tid >> 6] = s;
  __syncthreads();
  double tot = part[0] + part[1] + part[2] + part[3];
  double n = sqrt(tot);
  if (n < 1e-12) n = 1e-12;
  float inv = (float)(1.0 / n);
  cbh[(size_t)k * 512 + tid] = (_Float16)(c0 * inv);
  cbh[(size_t)k * 512 + 256 + tid] = (_Float16)(c1 * inv);
  if (tid == 0) nrm[k] = n;
}

// ---------------- top-2 insert (higher value wins; tie -> smaller index) ----------------
__device__ __forceinline__ void t2merge(float& v0, int& i0, float& v1, int& i1, float w, int j) {
  if (w > v0 || (w == v0 && j < i0)) {
    v1 = v0; i1 = i0; v0 = w; i0 = j;
  } else if (w > v1 || (w == v1 && j < i1)) {
    v1 = w; i1 = j;
  }
}

// ---------------- f16 MFMA GEMM (M=16384, N=8192, K=512), epilogue = per-row top2/64cols ----
__global__ __launch_bounds__(256) void k_gemm_top2(const _Float16* __restrict__ A,
                                                   const _Float16* __restrict__ Bw,
                                                   float4* __restrict__ top2) {
  __shared__ alignas(16) _Float16 Ah[128 * 64];
  __shared__ alignas(16) _Float16 Bh[128 * 64];
  int bid = blockIdx.x;
  int swz = ((bid & 7) << 10) | (bid >> 3);     // XCD swizzle, 8192 % 8 == 0 -> bijective
  int bn = swz >> 7;                            // 0..63
  int bm = swz & 127;                           // 0..127
  int tid = threadIdx.x;
  int w = tid >> 6, lane = tid & 63;
  int wm = w >> 1, wn = w & 1;                  // 2x2 wave grid, each wave 64x64
  int lr = lane >> 3, lc = lane & 7;            // staging lane -> (row-in-chunk, 8-half group)
  int cgrp = lane & 15, rgrp = lane >> 4;       // MFMA fragment coords
  floatx4 acc[4][4];
#pragma unroll
  for (int i = 0; i < 4; ++i)
#pragma unroll
    for (int j = 0; j < 4; ++j) acc[i][j] = floatx4{0.f, 0.f, 0.f, 0.f};
  const _Float16* Ab = A + ((size_t)(bm * 128 + lr)) * 512 + lc * 8;
  const _Float16* Bb = Bw + ((size_t)(bn * 128 + lr)) * 512 + lc * 8;
  for (int kt = 0; kt < 8; ++kt) {
#pragma unroll
    for (int i = 0; i < 4; ++i) {
      int c = w * 4 + i;                        // 16 chunks of 8 rows x 64 halves (1 KB each)
      GLD(Ab + (size_t)c * 8 * 512 + kt * 64, Ah + c * 512);
      GLD(Bb + (size_t)c * 8 * 512 + kt * 64, Bh + c * 512);
    }
    asm volatile("s_waitcnt vmcnt(0)" ::: "memory");
    __syncthreads();
#pragma unroll
    for (int kk = 0; kk < 2; ++kk) {
      half8 af[4], bf[4];
#pragma unroll
      for (int f = 0; f < 4; ++f)
        af[f] = *(const half8*)(Ah + (wm * 64 + f * 16 + cgrp) * 64 + kk * 32 + rgrp * 8);
#pragma unroll
      for (int f = 0; f < 4; ++f)
        bf[f] = *(const half8*)(Bh + (wn * 64 + f * 16 + cgrp) * 64 + kk * 32 + rgrp * 8);
#pragma unroll
      for (int fm = 0; fm < 4; ++fm)
#pragma unroll
        for (int fn = 0; fn < 4; ++fn)
          acc[fm][fn] = __builtin_amdgcn_mfma_f32_16x16x32_f16(af[fm], bf[fn], acc[fm][fn], 0, 0, 0);
    }
    __syncthreads();
  }
  // epilogue: per output row, top-2 over this wave's 64 columns
#pragma unroll
  for (int fm = 0; fm < 4; ++fm) {
#pragma unroll
    for (int r = 0; r < 4; ++r) {
      float v0 = -3.4e38f, v1 = -3.4e38f;
      int i0 = 0x7fffffff, i1 = 0x7fffffff;
#pragma unroll
      for (int fn = 0; fn < 4; ++fn) {
        float vv = acc[fm][fn][r];
        int cc = bn * 128 + wn * 64 + fn * 16 + cgrp;
        t2merge(v0, i0, v1, i1, vv, cc);
      }
#pragma unroll
      for (int m = 1; m < 16; m <<= 1) {        // reduce across the 16 column-lanes
        float ov0 = __shfl_xor(v0, m, 64);
        int oi0 = __shfl_xor(i0, m, 64);
        float ov1 = __shfl_xor(v1, m, 64);
        int oi1 = __shfl_xor(i1, m, 64);
        t2merge(v0, i0, v1, i1, ov0, oi0);
        t2merge(v0, i0, v1, i1, ov1, oi1);
      }
      if (cgrp == 0) {
        int grow = bm * 128 + wm * 64 + fm * 16 + rgrp * 4 + r;
        int c64 = bn * 2 + wn;                  // 128 column-blocks of 64
        float4 st;
        st.x = v0; st.y = v1;
        st.z = __int_as_float(i0); st.w = __int_as_float(i1);
        top2[(size_t)grow * 128 + c64] = st;
      }
    }
  }
}

// ---------------- finalize: exact fp64 rescore of in-margin candidates, write indices ----
__global__ __launch_bounds__(64) void k_finalize(const float4* __restrict__ top2,
                                                 const float* __restrict__ encT,
                                                 const float* __restrict__ cb,
                                                 const double* __restrict__ nrm,
                                                 float* __restrict__ idxf) {
  int row = blockIdx.x;
  int lane = threadIdx.x;
  float4 e0 = top2[(size_t)row * 128 + lane * 2];
  float4 e1 = top2[(size_t)row * 128 + lane * 2 + 1];
  float mx = fmaxf(e0.x, e1.x);
#pragma unroll
  for (int m = 1; m < 64; m <<= 1) mx = fmaxf(mx, __shfl_xor(mx, m, 64));
  float thr = mx - MARGIN;
  float ev[8];
#pragma unroll
  for (int x = 0; x < 8; ++x) ev[x] = encT[(size_t)row * 512 + lane * 8 + x];
  double bs = -1e300;
  int bk = 0x7fffffff;
  float cv[4] = {e0.x, e0.y, e1.x, e1.y};
  int ci[4] = {__float_as_int(e0.z), __float_as_int(e0.w),
               __float_as_int(e1.z), __float_as_int(e1.w)};
#pragma unroll
  for (int j = 0; j < 4; ++j) {
    unsigned long long ball = __ballot(cv[j] >= thr);
    while (ball) {
      int src = __ffsll(ball) - 1;
      ball &= ball - 1;
      int k = __shfl(ci[j], src, 64);
      const float* crow = cb + (size_t)k * 512;
      double s = 0.0;
#pragma unroll
      for (int x = 0; x < 8; ++x) s += (double)ev[x] * (double)crow[lane * 8 + x];
#pragma unroll
      for (int m = 1; m < 64; m <<= 1) s += __shfl_xor(s, m, 64);
      double sc = s / nrm[k];
      if (sc > bs || (sc == bs && k < bk)) { bs = sc; bk = k; }
    }
  }
  if (lane == 0) idxf[row] = (float)bk;
}

// ---------------- gather: z_q / z_q_out = codebook[idx] (B,D,T-layout) * mask ----------------
__global__ __launch_bounds__(256) void k_gather(const float* __restrict__ cb,
                                                const float* __restrict__ idxf,
                                                const float* __restrict__ mask,
                                                float* __restrict__ zq,
                                                float* __restrict__ zqout) {
  int bid = blockIdx.x;
  int db = bid & 7, tb = (bid >> 3) & 31, b = bid >> 8;
  int d0 = db * 64, t0 = tb * 64;
  __shared__ float tile[64][65];
  __shared__ int kidx[64];
  __shared__ float mk[64];
  int tid = threadIdx.x, w = tid >> 6, lane = tid & 63;
  if (tid < 64) {
    kidx[tid] = (int)idxf[b * T_ + t0 + tid];
    mk[tid] = mask[b * T_ + t0 + tid];
  }
  __syncthreads();
#pragma unroll
  for (int it = 0; it < 16; ++it) {
    int tl = it * 4 + w;
    int k = kidx[tl];
    tile[lane][tl] = cb[(size_t)k * D_ + d0 + lane];       // coalesced cb row segment
  }
  __syncthreads();
#pragma unroll
  for (int it = 0; it < 16; ++it) {
    int dl = it * 4 + w;
    float v = tile[dl][lane] * mk[lane];
    size_t off = ((size_t)(b * D_ + d0 + dl)) * T_ + t0 + lane;  // coalesced along t
    zq[off] = v;
    zqout[off] = v;
  }
}

// ---------------- z_e = z (verbatim copy) ----------------
__global__ __launch_bounds__(256) void k_copy_ze(const float4* __restrict__ z4,
                                                 float4* __restrict__ o4) {
  size_t n4 = ZSZ / 4;
  for (size_t i = (size_t)blockIdx.x * 256 + threadIdx.x; i < n4; i += (size_t)gridDim.x * 256)
    o4[i] = z4[i];
}

extern "C" void kernel_launch(void* const* d_in, const int* in_sizes, int n_in,
                              void* d_out, int out_size, void* d_ws, size_t ws_size,
                              hipStream_t stream) {
  const float* z = (const float*)d_in[0];
  const float* mask = (const float*)d_in[1];
  const float* cb = (const float*)d_in[2];
  float* out = (float*)d_out;
  char* o = (char*)d_out;
  // ALL scratch lives inside d_out (100.7 MB); d_ws untouched (ws_size unknown/unsafe).
  //   seg0 [0,      SEGB): final z_q      | staging: encTh (16.8M) + cbh (8.4M) + nrm (64K)
  //   seg1 [SEGB,  2SEGB): final z_e      | staging: top2 (16384 x 128 float4 = 33.5M)
  //   seg2 [2SEGB, 3SEGB): final z_q_out  | staging: encT f32 (exactly 33.55M)
  //   seg3 [3SEGB, ...  ): final indices (float; finalize writes, gather reads back)
  // Write order: prep(seg0,seg2) -> gemm(seg1) -> finalize(seg3) -> gather(seg0,seg2) -> copy(seg1)
  _Float16* encTh = (_Float16*)(o);                       // 16,777,216 B
  _Float16* cbh   = (_Float16*)(o + 16777216);            //  8,388,608 B
  double*   nrm   = (double*)(o + 25165824);              //     65,536 B  (< SEGB total)
  float4*   top2  = (float4*)(o + SEGB);                  // 33,554,432 B
  float*    encT  = (float*)(o + 2 * SEGB);               // 33,554,432 B
  float*    idxf  = out + 3 * ZSZ;                        // 16384 floats (final output 3)
  float*    zq    = out;                                  // final output 0
  float*    ze    = out + ZSZ;                            // final output 1
  float*    zqout = out + 2 * ZSZ;                        // final output 2

  k_prep_z<<<2048, 256, 0, stream>>>(z, encT, encTh);
  k_prep_cb<<<8192, 256, 0, stream>>>(cb, cbh, nrm);
  k_gemm_top2<<<8192, 256, 0, stream>>>(encTh, cbh, top2);
  k_finalize<<<16384, 64, 0, stream>>>(top2, encT, cb, nrm, idxf);
  k_gather<<<2048, 256, 0, stream>>>(cb, idxf, mask, zq, zqout);
  k_copy_ze<<<2048, 256, 0, stream>>>((const float4*)z, (float4*)ze);
}

// Round 3
// 1244.402 us; speedup vs baseline: 1.2544x; 1.2544x over previous
//
#include <hip/hip_runtime.h>
#include <hip/hip_fp16.h>

typedef _Float16 half8 __attribute__((ext_vector_type(8)));
typedef float floatx4 __attribute__((ext_vector_type(4)));

#define GLD(gp, lp) __builtin_amdgcn_global_load_lds( \
    (const __attribute__((address_space(1))) void*)(gp), \
    (__attribute__((address_space(3))) void*)(lp), 16, 0, 0)

static constexpr int B_ = 8, D_ = 512, T_ = 2048, K_ = 8192;
static constexpr size_t ZSZ = (size_t)B_ * D_ * T_;   // 8388608 elems; one output segment
static constexpr size_t SEGB = ZSZ * 4;               // 33,554,432 bytes per segment
static constexpr float MARGIN = 0.02f;                // f16 screen err ~4e-3; 2x + slack

// ---------------- prep: transpose z (B,D,T) -> encT (BT,D) in f32 + f16 ----------------
__global__ __launch_bounds__(256) void k_prep_z(const float* __restrict__ z,
                                                float* __restrict__ encT,
                                                _Float16* __restrict__ encTh) {
  int bid = blockIdx.x;
  int db = bid & 7, tb = (bid >> 3) & 31, b = bid >> 8;   // 8 x 32 x 8 = 2048 blocks
  int d0 = db * 64, t0 = tb * 64;
  __shared__ float tz[64][65];
  int tid = threadIdx.x, w = tid >> 6, lane = tid & 63;
#pragma unroll
  for (int it = 0; it < 16; ++it) {
    int dl = it * 4 + w;
    tz[dl][lane] = z[((size_t)(b * D_ + d0 + dl)) * T_ + t0 + lane];  // coalesced along t
  }
  __syncthreads();
#pragma unroll
  for (int it = 0; it < 16; ++it) {
    int tl = it * 4 + w;
    size_t bt = (size_t)b * T_ + t0 + tl;
    float v = tz[lane][tl];                                // bank-spread (stride 65)
    encT[bt * D_ + d0 + lane] = v;                         // coalesced along d
    encTh[bt * D_ + d0 + lane] = (_Float16)v;
  }
}

// ---------------- prep: codebook norms (f64) + normalized f16 codebook ----------------
__global__ __launch_bounds__(256) void k_prep_cb(const float* __restrict__ cb,
                                                 _Float16* __restrict__ cbh,
                                                 double* __restrict__ nrm) {
  int k = blockIdx.x;
  int tid = threadIdx.x;
  float c0 = cb[(size_t)k * 512 + tid];
  float c1 = cb[(size_t)k * 512 + 256 + tid];
  double s = (double)c0 * c0 + (double)c1 * c1;
#pragma unroll
  for (int m = 1; m < 64; m <<= 1) s += __shfl_xor(s, m, 64);
  __shared__ double part[4];
  if ((tid & 63) == 0) part[tid >> 6] = s;
  __syncthreads();
  double tot = part[0] + part[1] + part[2] + part[3];
  double n = sqrt(tot);
  if (n < 1e-12) n = 1e-12;
  float inv = (float)(1.0 / n);
  cbh[(size_t)k * 512 + tid] = (_Float16)(c0 * inv);
  cbh[(size_t)k * 512 + 256 + tid] = (_Float16)(c1 * inv);
  if (tid == 0) nrm[k] = n;
}

// ---------------- top-2 insert (higher value wins; tie -> smaller index) ----------------
__device__ __forceinline__ void t2merge(float& v0, int& i0, float& v1, int& i1, float w, int j) {
  if (w > v0 || (w == v0 && j < i0)) {
    v1 = v0; i1 = i0; v0 = w; i0 = j;
  } else if (w > v1 || (w == v1 && j < i1)) {
    v1 = w; i1 = j;
  }
}

// ---------------- f16 MFMA GEMM (M=16384, N=8192, K=512), epilogue = per-row top2/64cols ----
// m97 structure (128^2 tile, single-buffer, 2-barrier) + T2 XOR-swizzle via pre-swizzled
// global source (rule #21: gload_lds dest stays linear) + forced 3 blocks/CU.
__global__ __launch_bounds__(256, 3) void k_gemm_top2(const _Float16* __restrict__ A,
                                                      const _Float16* __restrict__ Bw,
                                                      float4* __restrict__ top2) {
  __shared__ alignas(16) _Float16 Ah[128 * 64];
  __shared__ alignas(16) _Float16 Bh[128 * 64];
  int bid = blockIdx.x;
  int swz = ((bid & 7) << 10) | (bid >> 3);     // XCD swizzle, 8192 % 8 == 0 -> bijective
  int bn = swz >> 7;                            // 0..63
  int bm = swz & 127;                           // 0..127
  int tid = threadIdx.x;
  int w = tid >> 6, lane = tid & 63;
  int wm = w >> 1, wn = w & 1;                  // 2x2 wave grid, each wave 64x64
  // staging: chunk = 8 rows x 64 halves; lane l -> row l>>3, swizzled col ((l&7)^(l>>3))*8.
  // LDS write is linear (base + l*16B); source col pre-swizzled so that LDS holds
  // swizzled layout: LDS(row, c) = global(row, c ^ ((row&7)*8))   [halves]
  int srow = lane >> 3;
  int scol = ((lane & 7) ^ srow) * 8;
  int cgrp = lane & 15, rgrp = lane >> 4;       // MFMA fragment coords
  floatx4 acc[4][4];
#pragma unroll
  for (int i = 0; i < 4; ++i)
#pragma unroll
    for (int j = 0; j < 4; ++j) acc[i][j] = floatx4{0.f, 0.f, 0.f, 0.f};
  const _Float16* Ab = A + ((size_t)(bm * 128 + srow)) * 512 + scol;
  const _Float16* Bb = Bw + ((size_t)(bn * 128 + srow)) * 512 + scol;
  // fragment-read swizzle (halves): col ^ ((row&7)<<3)
  int arow0 = wm * 64 + cgrp;                   // + f*16
  int brow0 = wn * 64 + cgrp;
  for (int kt = 0; kt < 8; ++kt) {
#pragma unroll
    for (int i = 0; i < 4; ++i) {
      int c = w * 4 + i;                        // 16 chunks of 8 rows x 64 halves (1 KB each)
      GLD(Ab + (size_t)c * 8 * 512 + kt * 64, Ah + c * 512);
      GLD(Bb + (size_t)c * 8 * 512 + kt * 64, Bh + c * 512);
    }
    __syncthreads();                            // compiler emits vmcnt(0) drain + barrier
#pragma unroll
    for (int kk = 0; kk < 2; ++kk) {
      half8 af[4], bf[4];
#pragma unroll
      for (int f = 0; f < 4; ++f) {
        int row = arow0 + f * 16;
        af[f] = *(const half8*)(Ah + row * 64 + ((kk * 32 + rgrp * 8) ^ ((row & 7) << 3)));
      }
#pragma unroll
      for (int f = 0; f < 4; ++f) {
        int row = brow0 + f * 16;
        bf[f] = *(const half8*)(Bh + row * 64 + ((kk * 32 + rgrp * 8) ^ ((row & 7) << 3)));
      }
#pragma unroll
      for (int fm = 0; fm < 4; ++fm)
#pragma unroll
        for (int fn = 0; fn < 4; ++fn)
          acc[fm][fn] = __builtin_amdgcn_mfma_f32_16x16x32_f16(af[fm], bf[fn], acc[fm][fn], 0, 0, 0);
    }
    __syncthreads();
  }
  // epilogue: per output row, top-2 over this wave's 64 columns
#pragma unroll
  for (int fm = 0; fm < 4; ++fm) {
#pragma unroll
    for (int r = 0; r < 4; ++r) {
      float v0 = -3.4e38f, v1 = -3.4e38f;
      int i0 = 0x7fffffff, i1 = 0x7fffffff;
#pragma unroll
      for (int fn = 0; fn < 4; ++fn) {
        float vv = acc[fm][fn][r];
        int cc = bn * 128 + wn * 64 + fn * 16 + cgrp;
        t2merge(v0, i0, v1, i1, vv, cc);
      }
#pragma unroll
      for (int m = 1; m < 16; m <<= 1) {        // reduce across the 16 column-lanes
        float ov0 = __shfl_xor(v0, m, 64);
        int oi0 = __shfl_xor(i0, m, 64);
        float ov1 = __shfl_xor(v1, m, 64);
        int oi1 = __shfl_xor(i1, m, 64);
        t2merge(v0, i0, v1, i1, ov0, oi0);
        t2merge(v0, i0, v1, i1, ov1, oi1);
      }
      if (cgrp == 0) {
        int grow = bm * 128 + wm * 64 + fm * 16 + rgrp * 4 + r;
        int c64 = bn * 2 + wn;                  // 128 column-blocks of 64
        float4 st;
        st.x = v0; st.y = v1;
        st.z = __int_as_float(i0); st.w = __int_as_float(i1);
        top2[(size_t)grow * 128 + c64] = st;
      }
    }
  }
}

// ---------------- finalize: exact fp64 rescore of in-margin candidates, write indices ----
__global__ __launch_bounds__(64) void k_finalize(const float4* __restrict__ top2,
                                                 const float* __restrict__ encT,
                                                 const float* __restrict__ cb,
                                                 const double* __restrict__ nrm,
                                                 float* __restrict__ idxf) {
  int row = blockIdx.x;
  int lane = threadIdx.x;
  float4 e0 = top2[(size_t)row * 128 + lane * 2];
  float4 e1 = top2[(size_t)row * 128 + lane * 2 + 1];
  float mx = fmaxf(e0.x, e1.x);
#pragma unroll
  for (int m = 1; m < 64; m <<= 1) mx = fmaxf(mx, __shfl_xor(mx, m, 64));
  float thr = mx - MARGIN;
  float ev[8];
#pragma unroll
  for (int x = 0; x < 8; ++x) ev[x] = encT[(size_t)row * 512 + lane * 8 + x];
  double bs = -1e300;
  int bk = 0x7fffffff;
  float cv[4] = {e0.x, e0.y, e1.x, e1.y};
  int ci[4] = {__float_as_int(e0.z), __float_as_int(e0.w),
               __float_as_int(e1.z), __float_as_int(e1.w)};
#pragma unroll
  for (int j = 0; j < 4; ++j) {
    unsigned long long ball = __ballot(cv[j] >= thr);
    while (ball) {
      int src = __ffsll(ball) - 1;
      ball &= ball - 1;
      int k = __shfl(ci[j], src, 64);
      const float* crow = cb + (size_t)k * 512;
      double s = 0.0;
#pragma unroll
      for (int x = 0; x < 8; ++x) s += (double)ev[x] * (double)crow[lane * 8 + x];
#pragma unroll
      for (int m = 1; m < 64; m <<= 1) s += __shfl_xor(s, m, 64);
      double sc = s / nrm[k];
      if (sc > bs || (sc == bs && k < bk)) { bs = sc; bk = k; }
    }
  }
  if (lane == 0) idxf[row] = (float)bk;
}

// ---------------- gather: z_q / z_q_out = codebook[idx] (B,D,T-layout) * mask ----------------
__global__ __launch_bounds__(256) void k_gather(const float* __restrict__ cb,
                                                const float* __restrict__ idxf,
                                                const float* __restrict__ mask,
                                                float* __restrict__ zq,
                                                float* __restrict__ zqout) {
  int bid = blockIdx.x;
  int db = bid & 7, tb = (bid >> 3) & 31, b = bid >> 8;
  int d0 = db * 64, t0 = tb * 64;
  __shared__ float tile[64][65];
  __shared__ int kidx[64];
  __shared__ float mk[64];
  int tid = threadIdx.x, w = tid >> 6, lane = tid & 63;
  if (tid < 64) {
    kidx[tid] = (int)idxf[b * T_ + t0 + tid];
    mk[tid] = mask[b * T_ + t0 + tid];
  }
  __syncthreads();
#pragma unroll
  for (int it = 0; it < 16; ++it) {
    int tl = it * 4 + w;
    int k = kidx[tl];
    tile[lane][tl] = cb[(size_t)k * D_ + d0 + lane];       // coalesced cb row segment
  }
  __syncthreads();
#pragma unroll
  for (int it = 0; it < 16; ++it) {
    int dl = it * 4 + w;
    float v = tile[dl][lane] * mk[lane];
    size_t off = ((size_t)(b * D_ + d0 + dl)) * T_ + t0 + lane;  // coalesced along t
    zq[off] = v;
    zqout[off] = v;
  }
}

// ---------------- z_e = z (verbatim copy) ----------------
__global__ __launch_bounds__(256) void k_copy_ze(const float4* __restrict__ z4,
                                                 float4* __restrict__ o4) {
  size_t n4 = ZSZ / 4;
  for (size_t i = (size_t)blockIdx.x * 256 + threadIdx.x; i < n4; i += (size_t)gridDim.x * 256)
    o4[i] = z4[i];
}

extern "C" void kernel_launch(void* const* d_in, const int* in_sizes, int n_in,
                              void* d_out, int out_size, void* d_ws, size_t ws_size,
                              hipStream_t stream) {
  const float* z = (const float*)d_in[0];
  const float* mask = (const float*)d_in[1];
  const float* cb = (const float*)d_in[2];
  float* out = (float*)d_out;
  char* o = (char*)d_out;
  // ALL scratch lives inside d_out (100.7 MB); d_ws untouched (ws_size unknown/unsafe).
  //   seg0 [0,      SEGB): final z_q      | staging: encTh (16.8M) + cbh (8.4M) + nrm (64K)
  //   seg1 [SEGB,  2SEGB): final z_e      | staging: top2 (16384 x 128 float4 = 33.5M)
  //   seg2 [2SEGB, 3SEGB): final z_q_out  | staging: encT f32 (exactly 33.55M)
  //   seg3 [3SEGB, ...  ): final indices (float; finalize writes, gather reads back)
  // Write order: prep(seg0,seg2) -> gemm(seg1) -> finalize(seg3) -> gather(seg0,seg2) -> copy(seg1)
  _Float16* encTh = (_Float16*)(o);                       // 16,777,216 B
  _Float16* cbh   = (_Float16*)(o + 16777216);            //  8,388,608 B
  double*   nrm   = (double*)(o + 25165824);              //     65,536 B  (< SEGB total)
  float4*   top2  = (float4*)(o + SEGB);                  // 33,554,432 B
  float*    encT  = (float*)(o + 2 * SEGB);               // 33,554,432 B
  float*    idxf  = out + 3 * ZSZ;                        // 16384 floats (final output 3)
  float*    zq    = out;                                  // final output 0
  float*    ze    = out + ZSZ;                            // final output 1
  float*    zqout = out + 2 * ZSZ;                        // final output 2

  k_prep_z<<<2048, 256, 0, stream>>>(z, encT, encTh);
  k_prep_cb<<<8192, 256, 0, stream>>>(cb, cbh, nrm);
  k_gemm_top2<<<8192, 256, 0, stream>>>(encTh, cbh, top2);
  k_finalize<<<16384, 64, 0, stream>>>(top2, encT, cb, nrm, idxf);
  k_gather<<<2048, 256, 0, stream>>>(cb, idxf, mask, zq, zqout);
  k_copy_ze<<<2048, 256, 0, stream>>>((const float4*)z, (float4*)ze);
}